// Round 8
// baseline (427.950 us; speedup 1.0000x reference)
//
#include <hip/hip_runtime.h>
#include <math.h>

#define N_ROWS 32768
#define D 256
#define K 1024
#define DEPTH 3
#define MARGIN 0.05f

typedef __bf16 bf16x8 __attribute__((ext_vector_type(8)));
typedef float f32x4 __attribute__((ext_vector_type(4)));
typedef __attribute__((ext_vector_type(8))) unsigned short u16x8;

// ---- ws layout (bytes) ----
// 0        idxAll[3][32768] int        -> 393216
// 393216   counts[3][1024] int         -> 405504   (memset each launch)
// 405504   ssepart[3][256] double      -> 411648
// 411648   e2f[3][1024] float          -> 423936
// 423936   cbp bf16 [3][1024][512]     -> 3569664

__device__ __forceinline__ void gload_lds16(const void* g, void* l) {
    __builtin_amdgcn_global_load_lds(
        (const __attribute__((address_space(1))) void*)g,
        (__attribute__((address_space(3))) void*)l, 16, 0, 0);
}

__device__ __forceinline__ unsigned short f2bf(float f) {
    unsigned u = __float_as_uint(f);
    return (unsigned short)((u + 0x7fffu + ((u >> 16) & 1u)) >> 16);
}

// cbs -> packed bf16 hi|lo codebooks + e2 (fused prep)
__global__ __launch_bounds__(256) void prep_kernel(
    const float* __restrict__ cbs, unsigned short* __restrict__ cbp,
    float* __restrict__ e2f)
{
    int t = blockIdx.x * 256 + threadIdx.x;    // 98304 = 3072 rows * 32
    int row = t >> 5;
    int k8 = (t & 31) * 8;
    size_t off = (size_t)row * D + k8;
    float4 v0 = *(const float4*)(cbs + off);
    float4 v1 = *(const float4*)(cbs + off + 4);
    float v[8] = {v0.x, v0.y, v0.z, v0.w, v1.x, v1.y, v1.z, v1.w};
    u16x8 hv, lv;
    double s = 0.0;
    #pragma unroll
    for (int j = 0; j < 8; ++j) {
        unsigned short h = f2bf(v[j]);
        hv[j] = h;
        float hf = __uint_as_float(((unsigned)h) << 16);
        lv[j] = f2bf(v[j] - hf);
        s = fma((double)v[j], (double)v[j], s);
    }
    *(u16x8*)(cbp + (size_t)row * 512 + k8) = hv;
    *(u16x8*)(cbp + (size_t)row * 512 + 256 + k8) = lv;
    #pragma unroll
    for (int m = 1; m <= 16; m <<= 1) s += __shfl_xor(s, m, 32);
    if ((threadIdx.x & 31) == 0) e2f[row] = (float)s;
}

// pack this thread's quarter-row (16 float4) into swizzled Bsm
__device__ __forceinline__ void pack_to_bsm(const float4* r4, __bf16* Bsm,
                                            int orow, int oq)
{
    const int rowbase = orow * 1024;
    const int sw = (orow & 7) << 4;
    #pragma unroll
    for (int j = 0; j < 8; ++j) {
        float v[8] = {r4[2*j].x, r4[2*j].y, r4[2*j].z, r4[2*j].w,
                      r4[2*j+1].x, r4[2*j+1].y, r4[2*j+1].z, r4[2*j+1].w};
        u16x8 hv, lv;
        #pragma unroll
        for (int e = 0; e < 8; ++e) {
            unsigned short h = f2bf(v[e]);
            hv[e] = h;
            float hf = __uint_as_float(((unsigned)h) << 16);
            lv[e] = f2bf(v[e] - hf);
        }
        int cH = oq * 8 + j;
        int cL = 32 + oq * 8 + j;
        *(u16x8*)((char*)Bsm + rowbase + ((cH << 4) ^ sw)) = hv;
        *(u16x8*)((char*)Bsm + rowbase + ((cL << 4) ^ sw)) = lv;
    }
}

// All 3 stages in one kernel. Block owns 128 rows. Residual in registers,
// packed residual persists in Bsm across stages. Argmin body == R7 (proven).
__global__ __launch_bounds__(512, 2) void rvq_fused_kernel(
    const float* __restrict__ z, const float* __restrict__ cbs,
    const unsigned short* __restrict__ cbp, const float* __restrict__ e2f,
    int* __restrict__ idxAll, int* __restrict__ counts,
    double* __restrict__ ssepart, float* __restrict__ qtot)
{
    __shared__ __align__(16) __bf16 Bsm[128 * 512];    // 128 KB resident rows
    __shared__ __align__(16) __bf16 Aw[2][256 * 32];   // 2 x 16 KB A windows

    const int tid = threadIdx.x;
    const int lane = tid & 63;
    const int w = tid >> 6;
    const int wm = w >> 1;
    const int wn = w & 1;
    const int hi = lane >> 4;
    const int lo16 = lane & 15;
    const int row0 = blockIdx.x * 128;
    const int orow = tid >> 2;       // owned row (0..127)
    const int oq = tid & 3;          // owned quarter

    // scratch carved from Aw[1] (free between stages; prefetch targets Aw[0])
    char* scr = (char*)Aw[1];
    float4* mb       = (float4*)scr;             // 8 KB merge scratch
    int*    idxS     = (int*)(scr + 8192);       // 128 ints
    int*    flagcntS = (int*)(scr + 8704);
    int*    flaglistS= (int*)(scr + 8768);       // 32 ints
    float4* rresV    = (float4*)(scr + 9216);    // 1 KB refine residual
    double* rd8      = (double*)(scr + 10240);
    int*    ri8      = (int*)(scr + 10304);
    double* sseW     = (double*)(scr + 10368);

    // ---- thread-constant addressing (identical to R7) ----
    int aPre[4], bPre[4];
    #pragma unroll
    for (int m = 0; m < 4; ++m) {
        int cl = wm * 64 + m * 16 + lo16;
        aPre[m] = cl * 64 + ((hi ^ ((cl ^ (cl >> 2)) & 3)) * 16);
    }
    #pragma unroll
    for (int n = 0; n < 4; ++n) {
        int rw = wn * 64 + n * 16 + lo16;
        bPre[n] = (rw * 1024 + hi * 16) ^ ((rw & 7) << 4);
    }
    int aSrc[2], aDst[2];
    #pragma unroll
    for (int r = 0; r < 2; ++r) {
        int q = r * 512 + tid;
        int c = q >> 2;
        int h = (q & 3) ^ ((c ^ (c >> 2)) & 3);
        aSrc[r] = c * 512 + h * 8;
        aDst[r] = q * 16;
    }

    // ---- prologue: z -> r regs -> Bsm pack; stage A win0 ----
    float4 r4[16];
    {
        const float4* zb = (const float4*)(z + (size_t)(row0 + orow) * 256 + oq * 64);
        #pragma unroll
        for (int j = 0; j < 16; ++j) r4[j] = zb[j];
        pack_to_bsm(r4, Bsm, orow, oq);
    }
    #pragma unroll
    for (int r = 0; r < 2; ++r)
        gload_lds16(cbp + aSrc[r], (char*)Aw[0] + aDst[r]);
    __syncthreads();

    for (int d = 0; d < DEPTH; ++d) {
        const unsigned short* cbpD = cbp + (size_t)d * (K * 512);
        const bool lastD = (d == DEPTH - 1);

        float d1[4], d2[4];
        int   i1[4], i2[4];
        #pragma unroll
        for (int n = 0; n < 4; ++n) {
            d1[n] = 3.4e38f; d2[n] = 3.4e38f;
            i1[n] = 0x7fffffff; i2[n] = 0x7fffffff;
        }

        // ================= argmin (R7 body) =================
        for (int cc = 0; cc < 4; ++cc) {
            const size_t cOff = (size_t)cc * 256 * 512;
            f32x4 acc[4][4];
            #pragma unroll
            for (int m = 0; m < 4; ++m)
                #pragma unroll
                for (int n = 0; n < 4; ++n)
                    acc[m][n] = (f32x4){0.f, 0.f, 0.f, 0.f};

            for (int jp = 0; jp < 8; ++jp) {
                {   // stage LO(jp) -> buf1
                    const int aOff = 256 + jp * 32;
                    #pragma unroll
                    for (int r = 0; r < 2; ++r)
                        gload_lds16(cbpD + cOff + aOff + aSrc[r], (char*)Aw[1] + aDst[r]);
                    asm volatile("s_waitcnt vmcnt(2)" ::: "memory");
                }
                __builtin_amdgcn_s_barrier();
                {
                    bf16x8 af[4];
                    #pragma unroll
                    for (int m = 0; m < 4; ++m)
                        af[m] = *(const bf16x8*)((const char*)Aw[0] + aPre[m]);
                    #pragma unroll
                    for (int g = 0; g < 2; ++g) {
                        const int bOffB = (g ? 512 : 0) + jp * 64;
                        bf16x8 bfv[4];
                        #pragma unroll
                        for (int n = 0; n < 4; ++n)
                            bfv[n] = *(const bf16x8*)((const char*)Bsm + (bPre[n] ^ bOffB));
                        #pragma unroll
                        for (int m = 0; m < 4; ++m)
                            #pragma unroll
                            for (int n = 0; n < 4; ++n)
                                acc[m][n] = __builtin_amdgcn_mfma_f32_16x16x32_bf16(
                                    af[m], bfv[n], acc[m][n], 0, 0, 0);
                    }
                }
                __builtin_amdgcn_s_barrier();
                if (!(lastD && cc == 3 && jp == 7)) {      // stage HI(next) -> buf0
                    const int jn = jp + 1;                 // jp=7 -> next cc / next codebook
                    const size_t cOffN = cOff + (size_t)(jn >> 3) * (256 * 512);
                    const int aOff = (jn & 7) * 32;
                    #pragma unroll
                    for (int r = 0; r < 2; ++r)
                        gload_lds16(cbpD + cOffN + aOff + aSrc[r], (char*)Aw[0] + aDst[r]);
                    asm volatile("s_waitcnt vmcnt(2)" ::: "memory");
                } else {
                    asm volatile("s_waitcnt vmcnt(0)" ::: "memory");
                }
                __builtin_amdgcn_s_barrier();
                {
                    bf16x8 af[4];
                    #pragma unroll
                    for (int m = 0; m < 4; ++m)
                        af[m] = *(const bf16x8*)((const char*)Aw[1] + aPre[m]);
                    const int bOffB = jp * 64;
                    bf16x8 bfv[4];
                    #pragma unroll
                    for (int n = 0; n < 4; ++n)
                        bfv[n] = *(const bf16x8*)((const char*)Bsm + (bPre[n] ^ bOffB));
                    #pragma unroll
                    for (int m = 0; m < 4; ++m)
                        #pragma unroll
                        for (int n = 0; n < 4; ++n)
                            acc[m][n] = __builtin_amdgcn_mfma_f32_16x16x32_bf16(
                                af[m], bfv[n], acc[m][n], 0, 0, 0);
                }
                __builtin_amdgcn_s_barrier();
            }

            // epilogue cc: dist = e2 - 2*dot; per-lane top-2
            const int cb0 = cc * 256;
            float e2a[4][4];
            #pragma unroll
            for (int m = 0; m < 4; ++m) {
                float4 t = *(const float4*)(e2f + d * K + cb0 + wm * 64 + m * 16 + hi * 4);
                e2a[m][0] = t.x; e2a[m][1] = t.y; e2a[m][2] = t.z; e2a[m][3] = t.w;
            }
            #pragma unroll
            for (int n = 0; n < 4; ++n)
                #pragma unroll
                for (int m = 0; m < 4; ++m)
                    #pragma unroll
                    for (int r = 0; r < 4; ++r) {
                        float dv = e2a[m][r] - 2.0f * acc[m][n][r];
                        int c = cb0 + wm * 64 + m * 16 + hi * 4 + r;
                        bool lt1 = dv < d1[n];
                        bool lt2 = dv < d2[n];
                        i2[n] = lt1 ? i1[n] : (lt2 ? c : i2[n]);
                        i1[n] = lt1 ? c : i1[n];
                        d2[n] = fminf(fmaxf(d1[n], dv), d2[n]);
                        d1[n] = fminf(d1[n], dv);
                    }
        }

        // butterfly merge across hi-groups
        #pragma unroll
        for (int n = 0; n < 4; ++n) {
            #pragma unroll
            for (int mk = 0; mk < 2; ++mk) {
                int mask = mk ? 32 : 16;
                float od1 = __shfl_xor(d1[n], mask, 64);
                float od2 = __shfl_xor(d2[n], mask, 64);
                int   oi1 = __shfl_xor(i1[n], mask, 64);
                int   oi2 = __shfl_xor(i2[n], mask, 64);
                if (od1 < d1[n] || (od1 == d1[n] && oi1 < i1[n])) { d2[n] = d1[n]; i2[n] = i1[n]; d1[n] = od1; i1[n] = oi1; }
                else if (od1 < d2[n] || (od1 == d2[n] && oi1 < i2[n])) { d2[n] = od1; i2[n] = oi1; }
                if (od2 < d1[n] || (od2 == d1[n] && oi2 < i1[n])) { d2[n] = d1[n]; i2[n] = i1[n]; d1[n] = od2; i1[n] = oi2; }
                else if (od2 < d2[n] || (od2 == d2[n] && oi2 < i2[n])) { d2[n] = od2; i2[n] = oi2; }
            }
        }

        if (tid == 0) *flagcntS = 0;
        if (lane < 16) {
            #pragma unroll
            for (int n = 0; n < 4; ++n)
                mb[wm * 128 + wn * 64 + n * 16 + lo16] =
                    make_float4(d1[n], d2[n], __int_as_float(i1[n]), __int_as_float(i2[n]));
        }
        __syncthreads();
        if (tid < 128) {
            float fd1 = 3.4e38f, fd2 = 3.4e38f;
            int   fi1 = 0x7fffffff, fi2 = 0x7fffffff;
            #pragma unroll
            for (int pc = 0; pc < 4; ++pc) {
                float4 p = mb[pc * 128 + tid];
                float pd1 = p.x, pd2 = p.y;
                int   pi1 = __float_as_int(p.z), pi2 = __float_as_int(p.w);
                if (pd1 < fd1 || (pd1 == fd1 && pi1 < fi1)) { fd2 = fd1; fi2 = fi1; fd1 = pd1; fi1 = pi1; }
                else if (pd1 < fd2 || (pd1 == fd2 && pi1 < fi2)) { fd2 = pd1; fi2 = pi1; }
                if (pd2 < fd1 || (pd2 == fd1 && pi2 < fi1)) { fd2 = fd1; fi2 = fi1; fd1 = pd2; fi1 = pi2; }
                else if (pd2 < fd2 || (pd2 == fd2 && pi2 < fi2)) { fd2 = pd2; fi2 = pi2; }
            }
            idxS[tid] = fi1;
            if (fd2 - fd1 < MARGIN) {
                int pos = atomicAdd(flagcntS, 1);
                if (pos < 32) flaglistS[pos] = tid;
            }
        }
        __syncthreads();

        // ============ in-block exact fp64 refine (rare) ============
        int cnt = *flagcntS;
        if (cnt > 32) cnt = 32;
        for (int f = 0; f < cnt; ++f) {
            int lr = flaglistS[f];
            if (orow == lr) {
                #pragma unroll
                for (int j = 0; j < 16; ++j) rresV[oq * 16 + j] = r4[j];
            }
            __syncthreads();
            double best = 1e300; int bi = 0;
            #pragma unroll
            for (int cd = 0; cd < 2; ++cd) {
                int c = tid * 2 + cd;
                const float4* cp = (const float4*)(cbs + (size_t)d * (K * D) + (size_t)c * 256);
                double s = 0.0;
                for (int k = 0; k < 64; ++k) {
                    float4 cv = cp[k];
                    float4 rv = rresV[k];
                    double a0 = (double)rv.x - (double)cv.x; s = fma(a0, a0, s);
                    double a1 = (double)rv.y - (double)cv.y; s = fma(a1, a1, s);
                    double a2 = (double)rv.z - (double)cv.z; s = fma(a2, a2, s);
                    double a3 = (double)rv.w - (double)cv.w; s = fma(a3, a3, s);
                }
                if (s < best || (s == best && c < bi)) { best = s; bi = c; }
            }
            #pragma unroll
            for (int m = 1; m <= 32; m <<= 1) {
                double od = __shfl_xor(best, m, 64);
                int oi = __shfl_xor(bi, m, 64);
                if (od < best || (od == best && oi < bi)) { best = od; bi = oi; }
            }
            if (lane == 0) { rd8[w] = best; ri8[w] = bi; }
            __syncthreads();
            if (tid == 0) {
                double bb = rd8[0]; int bj = ri8[0];
                for (int ww = 1; ww < 8; ++ww)
                    if (rd8[ww] < bb || (rd8[ww] == bb && ri8[ww] < bj)) { bb = rd8[ww]; bj = ri8[ww]; }
                idxS[lr] = bj;
            }
            __syncthreads();
        }

        if (tid < 128) {
            idxAll[d * N_ROWS + row0 + tid] = idxS[tid];
            atomicAdd(counts + d * K + idxS[tid], 1);
        }
        __syncthreads();

        // ============ update: r -= cb[idx]; SSE; repack Bsm ============
        {
            int idx = idxS[orow];
            const float4* cp = (const float4*)(cbs + (size_t)d * (K * D)
                                               + (size_t)idx * 256 + oq * 64);
            double s = 0.0;
            #pragma unroll
            for (int j = 0; j < 16; ++j) {
                float4 cv = cp[j];
                r4[j].x -= cv.x; r4[j].y -= cv.y; r4[j].z -= cv.z; r4[j].w -= cv.w;
                s = fma((double)r4[j].x, (double)r4[j].x, s);
                s = fma((double)r4[j].y, (double)r4[j].y, s);
                s = fma((double)r4[j].z, (double)r4[j].z, s);
                s = fma((double)r4[j].w, (double)r4[j].w, s);
            }
            if (!lastD) pack_to_bsm(r4, Bsm, orow, oq);
            #pragma unroll
            for (int m = 1; m <= 32; m <<= 1) s += __shfl_xor(s, m, 64);
            if (lane == 0) sseW[w] = s;
            __syncthreads();
            if (tid == 0) {
                double t8 = 0.0;
                for (int ww = 0; ww < 8; ++ww) t8 += sseW[ww];
                ssepart[d * 256 + blockIdx.x] = t8;
            }
            __syncthreads();
        }
    }

    // ---- epilogue: qtot = z - r_final ----
    {
        const float4* zb = (const float4*)(z + (size_t)(row0 + orow) * 256 + oq * 64);
        float4* qb = (float4*)(qtot + (size_t)(row0 + orow) * 256 + oq * 64);
        #pragma unroll
        for (int j = 0; j < 16; ++j) {
            float4 zv = zb[j];
            float4 o;
            o.x = zv.x - r4[j].x; o.y = zv.y - r4[j].y;
            o.z = zv.z - r4[j].z; o.w = zv.w - r4[j].w;
            qb[j] = o;
        }
    }
}

// compose + perplexity + loss in one tiny kernel
__global__ void final_kernel(const int* __restrict__ idxAll, const int* __restrict__ counts,
                             const double* __restrict__ ssepart,
                             float* __restrict__ loss, float* __restrict__ comp,
                             float* __restrict__ perps)
{
    __shared__ double red[16];
    __shared__ double lossAcc;
    const int tid = threadIdx.x;   // 1024 threads
    for (int n = tid; n < N_ROWS; n += 1024) {
        int v = idxAll[n] + (idxAll[N_ROWS + n] << 10) + (idxAll[2 * N_ROWS + n] << 20);
        comp[n] = (float)v;
    }
    if (tid == 0) lossAcc = 0.0;
    __syncthreads();
    for (int d = 0; d < DEPTH; ++d) {
        double p = (double)counts[d * K + tid] / 32768.0;
        double s = p * log(p + 1e-10);
        double q = (tid < 256) ? ssepart[d * 256 + tid] : 0.0;
        for (int o = 32; o > 0; o >>= 1) {
            s += __shfl_down(s, o, 64);
            q += __shfl_down(q, o, 64);
        }
        if ((tid & 63) == 0) red[tid >> 6] = s;
        __syncthreads();
        if (tid == 0) {
            double tot = 0.0;
            for (int i = 0; i < 16; ++i) tot += red[i];
            perps[d] = (float)exp(-tot);
        }
        __syncthreads();
        if ((tid & 63) == 0) red[tid >> 6] = q;
        __syncthreads();
        if (tid == 0) {
            double tq = 0.0;
            for (int i = 0; i < 16; ++i) tq += red[i];
            lossAcc += tq;
        }
        __syncthreads();
    }
    if (tid == 0)
        loss[0] = (float)(1.25 * lossAcc / 8388608.0);
}

extern "C" void kernel_launch(void* const* d_in, const int* in_sizes, int n_in,
                              void* d_out, int out_size, void* d_ws, size_t ws_size,
                              hipStream_t stream)
{
    const float* z   = (const float*)d_in[0];
    const float* cbs = (const float*)d_in[1];
    float* out = (float*)d_out;
    char*  ws  = (char*)d_ws;

    int*            idxAll   = (int*)ws;
    int*            counts   = (int*)(ws + 393216);
    double*         ssepart  = (double*)(ws + 405504);
    float*          e2f      = (float*)(ws + 411648);
    unsigned short* cbp      = (unsigned short*)(ws + 423936);

    float* qtot  = out;                       // 8388608 elems
    float* loss  = out + 8388608;             // 1
    float* comp  = out + 8388609;             // 32768
    float* perps = out + 8388609 + 32768;     // 3

    hipMemsetAsync(counts, 0, 12288, stream);

    prep_kernel<<<384, 256, 0, stream>>>(cbs, cbp, e2f);
    rvq_fused_kernel<<<256, 512, 0, stream>>>(
        z, cbs, cbp, e2f, idxAll, counts, ssepart, qtot);
    final_kernel<<<1, 1024, 0, stream>>>(idxAll, counts, ssepart, loss, comp, perps);
}